// Round 7
// baseline (156.428 us; speedup 1.0000x reference)
//
#include <hip/hip_runtime.h>
#include <hip/hip_bf16.h>

using short8 = __attribute__((ext_vector_type(8))) short;
using s16x4  = __attribute__((ext_vector_type(4))) short;
using f32x2  = __attribute__((ext_vector_type(2))) float;
using f32x4  = __attribute__((ext_vector_type(4))) float;
using f32x16 = __attribute__((ext_vector_type(16))) float;
using v2i    = __attribute__((ext_vector_type(2))) int;

#define DIM   768
#define D3    2304
#define SEQL  4096
#define NHEAD 12
#define NSPLIT 3

#if defined(__has_builtin)
#  if __has_builtin(__builtin_amdgcn_permlane32_swap)
#    define HAVE_PLSWAP 1
#  endif
#endif

static __device__ __forceinline__ short f2bs(float f) {
  union { __hip_bfloat16 h; short s; } u;
  u.h = __float2bfloat16(f);
  return u.s;
}

static __device__ __forceinline__ float bf2f(short s) {
  union { unsigned u; float f; } x;
  x.u = ((unsigned)(unsigned short)s) << 16;
  return x.f;
}

// packed f32x2 -> bf16x2 (RNE) in one instruction
static __device__ __forceinline__ int cvtpk(float lo, float hi) {
  int r;
  asm("v_cvt_pk_bf16_f32 %0, %1, %2" : "=v"(r) : "v"(lo), "v"(hi));
  return r;
}

// packed f32 add (CDNA VOP3P)
static __device__ __forceinline__ f32x2 pkadd(f32x2 a, f32x2 b) {
  f32x2 r;
  asm("v_pk_add_f32 %0, %1, %2" : "=v"(r) : "v"(a), "v"(b));
  return r;
}

// 2^x via v_exp_f32 (glibc macro collision prevents __exp2f on this toolchain)
static __device__ __forceinline__ float ex2(float x) {
  float r;
  asm("v_exp_f32 %0, %1" : "=v"(r) : "v"(x));
  return r;
}

static __device__ __forceinline__ void gl_lds16(const void* g, void* lds) {
  __builtin_amdgcn_global_load_lds((const __attribute__((address_space(1))) void*)g,
                                   (__attribute__((address_space(3))) void*)lds, 16, 0, 0);
}

// ---------- merged fp32 -> bf16 convert for x / w_qkv / w_proj ----------
// w_qkv rows 0..767 (Q weights) pre-scaled by SCALE*log2e.
__global__ __launch_bounds__(256) void cvt3_kernel(const float* __restrict__ x,
                                                   const float* __restrict__ wq,
                                                   const float* __restrict__ wp,
                                                   short* __restrict__ xb,
                                                   short* __restrict__ wqb,
                                                   short* __restrict__ wpb) {
  int b = blockIdx.x;
  const float* src; short* dst; int base; float sc = 1.0f;
  if (b < 3072)      { src = x;  dst = xb;  base = b * 1024; }
  else if (b < 4800) { src = wq; dst = wqb; base = (b - 3072) * 1024;
                       if (base < DIM * DIM) sc = 0.125f * 1.4426950408889634f; }
  else               { src = wp; dst = wpb; base = (b - 4800) * 1024; }
  int i = base + threadIdx.x * 4;
  f32x4 v = *(const f32x4*)(src + i);
  s16x4 o;
  #pragma unroll
  for (int j = 0; j < 4; ++j) o[j] = f2bs(v[j] * sc);
  *(s16x4*)(dst + i) = o;
}

// ---------- GEMM: C[m][n] = sum_k A[m][k]*B[n][k]; A:[M,K] bf16, B:[N,K] bf16 ----------
template <bool BF16OUT>
__global__ __launch_bounds__(256) void gemm_bt(const short* __restrict__ A,
                                               const short* __restrict__ B,
                                               short* __restrict__ Cb,
                                               float* __restrict__ Cf,
                                               const float* __restrict__ bias,
                                               int M, int N, int K) {
  __shared__ short As[128 * 64];
  __shared__ short Bs[128 * 64];
  const int tid = threadIdx.x;
  const int l  = tid & 63;
  const int w  = tid >> 6;
  const int g  = l >> 4, lc = l & 15;
  const int wr = w >> 1, wc = w & 1;
  const int m0 = blockIdx.y * 128, n0 = blockIdx.x * 128;
  const int trow = tid >> 3;
  const int tcol = (tid & 7) * 8;

  f32x4 acc[4][4];
  #pragma unroll
  for (int a = 0; a < 4; ++a)
    #pragma unroll
    for (int b = 0; b < 4; ++b) acc[a][b] = (f32x4){0.f, 0.f, 0.f, 0.f};

  for (int k0 = 0; k0 < K; k0 += 64) {
    __syncthreads();
    #pragma unroll
    for (int i = 0; i < 4; ++i) {
      int row = i * 32 + trow;
      gl_lds16(A + (size_t)(m0 + row) * K + k0 + tcol, As + row * 64 + tcol);
      gl_lds16(B + (size_t)(n0 + row) * K + k0 + tcol, Bs + row * 64 + tcol);
    }
    __syncthreads();
    #pragma unroll
    for (int kk = 0; kk < 2; ++kk) {
      short8 af[4], bf[4];
      #pragma unroll
      for (int mt = 0; mt < 4; ++mt)
        af[mt] = *(const short8*)(As + (wr * 64 + mt * 16 + lc) * 64 + kk * 32 + g * 8);
      #pragma unroll
      for (int nt = 0; nt < 4; ++nt)
        bf[nt] = *(const short8*)(Bs + (wc * 64 + nt * 16 + lc) * 64 + kk * 32 + g * 8);
      #pragma unroll
      for (int mt = 0; mt < 4; ++mt)
        #pragma unroll
        for (int nt = 0; nt < 4; ++nt)
          acc[mt][nt] = __builtin_amdgcn_mfma_f32_16x16x32_bf16(af[mt], bf[nt], acc[mt][nt], 0, 0, 0);
    }
  }

  #pragma unroll
  for (int mt = 0; mt < 4; ++mt)
    #pragma unroll
    for (int nt = 0; nt < 4; ++nt)
      #pragma unroll
      for (int r = 0; r < 4; ++r) {
        int row = m0 + wr * 64 + mt * 16 + g * 4 + r;
        int col = n0 + wc * 64 + nt * 16 + lc;
        float v = acc[mt][nt][r];
        if (BF16OUT) Cb[(size_t)row * N + col] = f2bs(v);
        else         Cf[(size_t)row * N + col] = v + bias[col];
      }
}

// ---------- V transpose: Vtg[head][d][j] = qkv[j][1536 + head*64 + d] ----------
__global__ __launch_bounds__(256) void transpose_v(const short* __restrict__ qkv,
                                                   short* __restrict__ vtg) {
  __shared__ short T[64][72];
  const int jt = blockIdx.x, hd = blockIdx.y, tid = threadIdx.x;
  #pragma unroll
  for (int i = 0; i < 2; ++i) {
    int idx = i * 256 + tid;
    int r = idx >> 3, c = idx & 7;
    *(short8*)&T[r][8 * c] =
        *(const short8*)(qkv + (size_t)(jt * 64 + r) * D3 + 1536 + hd * 64 + 8 * c);
  }
  __syncthreads();
  #pragma unroll
  for (int i = 0; i < 2; ++i) {
    int idx = i * 256 + tid;
    int d = idx >> 3, jc = idx & 7;
    short8 v;
    #pragma unroll
    for (int e = 0; e < 8; ++e) v[e] = T[8 * jc + e][d];
    *(short8*)(vtg + ((size_t)hd * 64 + d) * 4096 + jt * 64 + 8 * jc) = v;
  }
}

// ---------- flash attention, 32x32 swapped-QK^T, no-max softmax, KV-split ----------
// grid (SEQL/256, NHEAD, NSPLIT), 512 threads (8 waves). Wave w owns q rows
// blockIdx.x*256 + w*32 .. +31; 8 waves share each 64x64 KV tile (staging cost
// per wave-tile halved vs 4-wave). Split z covers KV tiles [z*64/3,(z+1)*64/3).
__global__ __launch_bounds__(512) void attn_kernel(const short* __restrict__ qkv,
                                                   const short* __restrict__ vtg,
                                                   short* __restrict__ O0,
                                                   short* __restrict__ O1,
                                                   short* __restrict__ O2,
                                                   float* __restrict__ Lp) {
  __shared__ short Ks[2][64 * 64];
  __shared__ short Vt[2][64 * 64];

  const int tid = threadIdx.x;
  const int l = tid & 63, w = tid >> 6;
  const int h = l >> 5;          // lane half
  const int q5 = l & 31;
  const int head = blockIdx.y;
  const int hoff = head * 64;
  const int qbase = blockIdx.x * 256 + w * 32;
  const int z = blockIdx.z;
  const int t0 = (z * 64) / 3, tend = ((z + 1) * 64) / 3;

  // Q B-fragments (rows q = qbase+q5), held for the whole loop
  short8 qf[4];
  {
    const short* qrow = qkv + (size_t)(qbase + q5) * D3 + hoff;
    #pragma unroll
    for (int ks = 0; ks < 4; ++ks) qf[ks] = *(const short8*)(qrow + ks * 16 + h * 8);
  }

  f32x16 o[2];
  #pragma unroll
  for (int nt = 0; nt < 2; ++nt)
    #pragma unroll
    for (int r = 0; r < 16; ++r) o[nt][r] = 0.f;
  float l_run = 0.f;
  const f32x16 zacc = {};            // zero C for the first QK^T k-slice

  const int swzK = 8 * (q5 & 7);     // read-side XOR for both K and V tiles

  // Incremental staging pointers (one 16B chunk per thread per tile).
  // K: row=tid>>3, col chunk XOR-permuted; V^T likewise.
  const int srow = tid >> 3, scol = (tid & 7) * 8;
  const int sswz = 8 * (srow & 7);
  const short* kptr = qkv + (size_t)(t0 * 64 + srow) * D3 + hoff + 768 + (scol ^ sswz);
  const short* vptr = vtg + ((size_t)hoff + srow) * 4096 + t0 * 64 + (scol ^ sswz);

  #define STAGE_KV(BUF)                                                          \
    {                                                                            \
      gl_lds16(kptr, &Ks[BUF][tid * 8]);                                         \
      gl_lds16(vptr, &Vt[BUF][tid * 8]);                                         \
      kptr += 64 * D3;                                                           \
      vptr += 64;                                                                \
    }

  STAGE_KV(0);
  asm volatile("s_waitcnt vmcnt(0)" ::: "memory");
  __syncthreads();

  for (int tt = t0; tt < tend; ++tt) {
    const int cur = (tt - t0) & 1;
    const bool pre = (tt + 1 < tend);
    if (pre) STAGE_KV(cur ^ 1);

    // ---- S^T = K Q^T : C[m=j][n=q], lane holds 32 j-values for q=q5 ----
    f32x16 p[2];
    __builtin_amdgcn_s_setprio(1);
    #pragma unroll
    for (int ks = 0; ks < 4; ++ks) {
      #pragma unroll
      for (int mt = 0; mt < 2; ++mt) {
        short8 kf = *(const short8*)(&Ks[cur][(mt * 32 + q5) * 64
                                              + ((ks * 16 + h * 8) ^ swzK)]);
        p[mt] = __builtin_amdgcn_mfma_f32_32x32x16_bf16(kf, qf[ks],
                                                        ks == 0 ? zacc : p[mt], 0, 0, 0);
      }
    }
    __builtin_amdgcn_s_setprio(0);

    // ---- p = exp2(s); own-half row-sum via packed adds ----
    f32x2 s2 = {0.f, 0.f};
    #pragma unroll
    for (int mt = 0; mt < 2; ++mt)
      #pragma unroll
      for (int i = 0; i < 8; ++i) {
        float pe0 = ex2(p[mt][2 * i]);
        float pe1 = ex2(p[mt][2 * i + 1]);
        p[mt][2 * i] = pe0;
        p[mt][2 * i + 1] = pe1;
        s2 = pkadd(s2, (f32x2){pe0, pe1});
      }
    l_run += s2[0] + s2[1];

    // ---- pack P to bf16 dwords via v_cvt_pk_bf16_f32 ----
    int D[16];
    #pragma unroll
    for (int mt = 0; mt < 2; ++mt)
      #pragma unroll
      for (int c = 0; c < 4; ++c) {
        D[mt * 8 + c * 2 + 0] = cvtpk(p[mt][4 * c + 0], p[mt][4 * c + 1]);
        D[mt * 8 + c * 2 + 1] = cvtpk(p[mt][4 * c + 2], p[mt][4 * c + 3]);
      }

    // ---- O += P V : per k-step, exchange dword pairs across lane halves ----
    __builtin_amdgcn_s_setprio(1);
    #pragma unroll
    for (int ks = 0; ks < 4; ++ks) {
      union { int i[4]; short8 s; } pa;
#ifdef HAVE_PLSWAP
      v2i r02 = __builtin_amdgcn_permlane32_swap(D[4 * ks + 0], D[4 * ks + 2], false, false);
      v2i r13 = __builtin_amdgcn_permlane32_swap(D[4 * ks + 1], D[4 * ks + 3], false, false);
      pa.i[0] = r02[0];
      pa.i[1] = r13[0];
      pa.i[2] = r02[1];
      pa.i[3] = r13[1];
#else
      const bool hh = (h != 0);
      const int a0 = D[4 * ks + 0], a1 = D[4 * ks + 1];
      const int b0 = D[4 * ks + 2], b1 = D[4 * ks + 3];
      int snd0 = hh ? a0 : b0, snd1 = hh ? a1 : b1;
      int r0 = __shfl_xor(snd0, 32), r1 = __shfl_xor(snd1, 32);
      pa.i[0] = hh ? r0 : a0;
      pa.i[1] = hh ? r1 : a1;
      pa.i[2] = hh ? b0 : r0;
      pa.i[3] = hh ? b1 : r1;
#endif
      #pragma unroll
      for (int nt = 0; nt < 2; ++nt) {
        short8 vf = *(const short8*)(&Vt[cur][(nt * 32 + q5) * 64
                                              + ((ks * 16 + h * 8) ^ swzK)]);
        o[nt] = __builtin_amdgcn_mfma_f32_32x32x16_bf16(pa.s, vf, o[nt], 0, 0, 0);
      }
    }
    __builtin_amdgcn_s_setprio(0);

    asm volatile("s_waitcnt vmcnt(0)" ::: "memory");
    __syncthreads();
  }

  // ---- epilogue: write unnormalized O (bf16) + l (f32) for this split ----
  float l_tot = l_run + __shfl_xor(l_run, 32);
  if (h == 0) Lp[(size_t)z * SEQL * NHEAD + (qbase + q5) * NHEAD + head] = l_tot;
  short* Ob = (z == 0) ? O0 : (z == 1) ? O1 : O2;
  #pragma unroll
  for (int nt = 0; nt < 2; ++nt)
    #pragma unroll
    for (int pp = 0; pp < 4; ++pp)
      #pragma unroll
      for (int r = 0; r < 4; ++r) {
        int q = qbase + r + 8 * pp + 4 * h;
        int d = hoff + nt * 32 + q5;
        Ob[(size_t)q * DIM + d] = f2bs(o[nt][4 * pp + r]);
      }
}

// ---------- combine: attb = (O0+O1+O2) / (l0+l1+l2), in place on O0 ----------
__global__ __launch_bounds__(256) void combine_kernel(short* __restrict__ O0,
                                                      const short* __restrict__ O1,
                                                      const short* __restrict__ O2,
                                                      const float* __restrict__ Lp) {
  int idx = blockIdx.x * 256 + threadIdx.x;
  int e0 = idx * 8;
  if (e0 >= SEQL * DIM) return;
  int q = e0 / DIM, col = e0 % DIM, head = col >> 6;
  int i0 = q * NHEAD + head;
  float lv = Lp[i0] + Lp[SEQL * NHEAD + i0] + Lp[2 * SEQL * NHEAD + i0];
  float inv = 1.0f / lv;
  short8 a = *(const short8*)(O0 + e0);
  short8 b = *(const short8*)(O1 + e0);
  short8 c = *(const short8*)(O2 + e0);
  short8 r;
  #pragma unroll
  for (int j = 0; j < 8; ++j)
    r[j] = f2bs((bf2f(a[j]) + bf2f(b[j]) + bf2f(c[j])) * inv);
  *(short8*)(O0 + e0) = r;
}

extern "C" void kernel_launch(void* const* d_in, const int* in_sizes, int n_in,
                              void* d_out, int out_size, void* d_ws, size_t ws_size,
                              hipStream_t stream) {
  (void)in_sizes; (void)n_in; (void)out_size; (void)ws_size;
  const float* x      = (const float*)d_in[0];
  const float* w_qkv  = (const float*)d_in[1];
  const float* w_proj = (const float*)d_in[2];
  const float* b_proj = (const float*)d_in[3];
  float* out = (float*)d_out;

  short* xb   = (short*)d_ws;                    // 4096*768  (dead after QKV gemm)
  short* wqb  = xb  + (size_t)SEQL * DIM;        // 2304*768  (dead after QKV gemm)
  short* wpb  = wqb + (size_t)D3 * DIM;          // 768*768
  short* qkvb = wpb + (size_t)DIM * DIM;         // 4096*2304
  short* attb = qkvb + (size_t)SEQL * D3;        // 4096*768  (O split 0, then attended)
  // reuse dead regions during attention:
  short* Opart1 = xb;                            // 4096*768 bf16 (O split 1)
  float* Lpart  = (float*)wqb;                   // NSPLIT*4096*12 f32
  // d_out (12.6 MB, dead until proj GEMM): first half V^T, second half O split 2
  short* vtg    = (short*)d_out;                 // [12][64][4096] bf16
  short* Opart2 = vtg + (size_t)SEQL * DIM;      // 4096*768 bf16

  cvt3_kernel<<<5376, 256, 0, stream>>>(x, w_qkv, w_proj, xb, wqb, wpb);
  gemm_bt<true ><<<dim3(D3 / 128, SEQL / 128), 256, 0, stream>>>(xb, wqb, qkvb, nullptr, nullptr, SEQL, D3, DIM);
  transpose_v<<<dim3(SEQL / 64, NHEAD), 256, 0, stream>>>(qkvb, vtg);
  attn_kernel<<<dim3(SEQL / 256, NHEAD, NSPLIT), 512, 0, stream>>>(qkvb, vtg, attb, Opart1, Opart2, Lpart);
  combine_kernel<<<SEQL * DIM / 8 / 256, 256, 0, stream>>>(attb, Opart1, Opart2, Lpart);
  gemm_bt<false><<<dim3(DIM / 128, SEQL / 128), 256, 0, stream>>>(attb, wpb, nullptr, out, b_proj, SEQL, DIM, DIM);
}

// Round 8
// 147.744 us; speedup vs baseline: 1.0588x; 1.0588x over previous
//
#include <hip/hip_runtime.h>
#include <hip/hip_bf16.h>

using short8 = __attribute__((ext_vector_type(8))) short;
using s16x4  = __attribute__((ext_vector_type(4))) short;
using f32x2  = __attribute__((ext_vector_type(2))) float;
using f32x4  = __attribute__((ext_vector_type(4))) float;
using f32x16 = __attribute__((ext_vector_type(16))) float;
using v2i    = __attribute__((ext_vector_type(2))) int;

#define DIM   768
#define D3    2304
#define SEQL  4096
#define NHEAD 12
#define NSPLIT 2

#if defined(__has_builtin)
#  if __has_builtin(__builtin_amdgcn_permlane32_swap)
#    define HAVE_PLSWAP 1
#  endif
#endif

static __device__ __forceinline__ short f2bs(float f) {
  union { __hip_bfloat16 h; short s; } u;
  u.h = __float2bfloat16(f);
  return u.s;
}

static __device__ __forceinline__ float bf2f(short s) {
  union { unsigned u; float f; } x;
  x.u = ((unsigned)(unsigned short)s) << 16;
  return x.f;
}

// packed f32x2 -> bf16x2 (RNE) in one instruction
static __device__ __forceinline__ int cvtpk(float lo, float hi) {
  int r;
  asm("v_cvt_pk_bf16_f32 %0, %1, %2" : "=v"(r) : "v"(lo), "v"(hi));
  return r;
}

// packed f32 add (CDNA VOP3P)
static __device__ __forceinline__ f32x2 pkadd(f32x2 a, f32x2 b) {
  f32x2 r;
  asm("v_pk_add_f32 %0, %1, %2" : "=v"(r) : "v"(a), "v"(b));
  return r;
}

// 2^x via v_exp_f32 (glibc macro collision prevents __exp2f on this toolchain)
static __device__ __forceinline__ float ex2(float x) {
  float r;
  asm("v_exp_f32 %0, %1" : "=v"(r) : "v"(x));
  return r;
}

static __device__ __forceinline__ void gl_lds16(const void* g, void* lds) {
  __builtin_amdgcn_global_load_lds((const __attribute__((address_space(1))) void*)g,
                                   (__attribute__((address_space(3))) void*)lds, 16, 0, 0);
}

// ---------- merged fp32 -> bf16 convert for x / w_qkv / w_proj ----------
// w_qkv rows 0..767 (Q weights) pre-scaled by SCALE*log2e.
__global__ __launch_bounds__(256) void cvt3_kernel(const float* __restrict__ x,
                                                   const float* __restrict__ wq,
                                                   const float* __restrict__ wp,
                                                   short* __restrict__ xb,
                                                   short* __restrict__ wqb,
                                                   short* __restrict__ wpb) {
  int b = blockIdx.x;
  const float* src; short* dst; int base; float sc = 1.0f;
  if (b < 3072)      { src = x;  dst = xb;  base = b * 1024; }
  else if (b < 4800) { src = wq; dst = wqb; base = (b - 3072) * 1024;
                       if (base < DIM * DIM) sc = 0.125f * 1.4426950408889634f; }
  else               { src = wp; dst = wpb; base = (b - 4800) * 1024; }
  int i = base + threadIdx.x * 4;
  f32x4 v = *(const f32x4*)(src + i);
  s16x4 o;
  #pragma unroll
  for (int j = 0; j < 4; ++j) o[j] = f2bs(v[j] * sc);
  *(s16x4*)(dst + i) = o;
}

// ---------- GEMM: C[m][n] = sum_k A[m][k]*B[n][k]; A:[M,K] bf16, B:[N,K] bf16 ----------
template <bool BF16OUT>
__global__ __launch_bounds__(256) void gemm_bt(const short* __restrict__ A,
                                               const short* __restrict__ B,
                                               short* __restrict__ Cb,
                                               float* __restrict__ Cf,
                                               const float* __restrict__ bias,
                                               int M, int N, int K) {
  __shared__ short As[128 * 64];
  __shared__ short Bs[128 * 64];
  const int tid = threadIdx.x;
  const int l  = tid & 63;
  const int w  = tid >> 6;
  const int g  = l >> 4, lc = l & 15;
  const int wr = w >> 1, wc = w & 1;
  const int m0 = blockIdx.y * 128, n0 = blockIdx.x * 128;
  const int trow = tid >> 3;
  const int tcol = (tid & 7) * 8;

  f32x4 acc[4][4];
  #pragma unroll
  for (int a = 0; a < 4; ++a)
    #pragma unroll
    for (int b = 0; b < 4; ++b) acc[a][b] = (f32x4){0.f, 0.f, 0.f, 0.f};

  for (int k0 = 0; k0 < K; k0 += 64) {
    __syncthreads();
    #pragma unroll
    for (int i = 0; i < 4; ++i) {
      int row = i * 32 + trow;
      gl_lds16(A + (size_t)(m0 + row) * K + k0 + tcol, As + row * 64 + tcol);
      gl_lds16(B + (size_t)(n0 + row) * K + k0 + tcol, Bs + row * 64 + tcol);
    }
    __syncthreads();
    #pragma unroll
    for (int kk = 0; kk < 2; ++kk) {
      short8 af[4], bf[4];
      #pragma unroll
      for (int mt = 0; mt < 4; ++mt)
        af[mt] = *(const short8*)(As + (wr * 64 + mt * 16 + lc) * 64 + kk * 32 + g * 8);
      #pragma unroll
      for (int nt = 0; nt < 4; ++nt)
        bf[nt] = *(const short8*)(Bs + (wc * 64 + nt * 16 + lc) * 64 + kk * 32 + g * 8);
      #pragma unroll
      for (int mt = 0; mt < 4; ++mt)
        #pragma unroll
        for (int nt = 0; nt < 4; ++nt)
          acc[mt][nt] = __builtin_amdgcn_mfma_f32_16x16x32_bf16(af[mt], bf[nt], acc[mt][nt], 0, 0, 0);
    }
  }

  #pragma unroll
  for (int mt = 0; mt < 4; ++mt)
    #pragma unroll
    for (int nt = 0; nt < 4; ++nt)
      #pragma unroll
      for (int r = 0; r < 4; ++r) {
        int row = m0 + wr * 64 + mt * 16 + g * 4 + r;
        int col = n0 + wc * 64 + nt * 16 + lc;
        float v = acc[mt][nt][r];
        if (BF16OUT) Cb[(size_t)row * N + col] = f2bs(v);
        else         Cf[(size_t)row * N + col] = v + bias[col];
      }
}

// ---------- V transpose: Vtg[head][d][j] = qkv[j][1536 + head*64 + d] ----------
__global__ __launch_bounds__(256) void transpose_v(const short* __restrict__ qkv,
                                                   short* __restrict__ vtg) {
  __shared__ short T[64][72];
  const int jt = blockIdx.x, hd = blockIdx.y, tid = threadIdx.x;
  #pragma unroll
  for (int i = 0; i < 2; ++i) {
    int idx = i * 256 + tid;
    int r = idx >> 3, c = idx & 7;
    *(short8*)&T[r][8 * c] =
        *(const short8*)(qkv + (size_t)(jt * 64 + r) * D3 + 1536 + hd * 64 + 8 * c);
  }
  __syncthreads();
  #pragma unroll
  for (int i = 0; i < 2; ++i) {
    int idx = i * 256 + tid;
    int d = idx >> 3, jc = idx & 7;
    short8 v;
    #pragma unroll
    for (int e = 0; e < 8; ++e) v[e] = T[8 * jc + e][d];
    *(short8*)(vtg + ((size_t)hd * 64 + d) * 4096 + jt * 64 + 8 * jc) = v;
  }
}

// ---------- flash attention, 32x32 swapped-QK^T, no-max softmax, KV-split ----------
// grid (768) linear, XCD-chunk-swizzled -> (qtile, head, split). 256 threads
// (4 waves); wave w owns q rows qt*128 + w*32 .. +31. 3-deep LDS ring,
// ONE raw s_barrier per tile, counted vmcnt(4) (no vmcnt(0) drain in loop).
__global__ __launch_bounds__(256) void attn_kernel(const short* __restrict__ qkv,
                                                   const short* __restrict__ vtg,
                                                   short* __restrict__ O0,
                                                   short* __restrict__ O1,
                                                   float* __restrict__ Lp,
                                                   int tpb) {
  __shared__ short Ks[3][64 * 64];
  __shared__ short Vt[3][64 * 64];

  // XCD chunk swizzle: 768 blocks, 8 XCDs -> XCD k gets swz range [96k, 96k+96)
  // = 3 contiguous (head,split) groups -> KV working set ~1.5MB fits 4MB L2.
  const int lin = blockIdx.x;
  const int swz = (lin & 7) * 96 + (lin >> 3);
  const int qt   = swz & 31;          // 32 q-tiles
  const int head = (swz >> 5) % NHEAD;
  const int z    = swz / (32 * NHEAD);

  const int tid = threadIdx.x;
  const int l = tid & 63, w = tid >> 6;
  const int h = l >> 5;          // lane half
  const int q5 = l & 31;
  const int hoff = head * 64;
  const int qbase = qt * 128 + w * 32;
  const int t0 = z * tpb, tend = t0 + tpb;

  // Q B-fragments (rows q = qbase+q5), held for the whole loop
  short8 qf[4];
  {
    const short* qrow = qkv + (size_t)(qbase + q5) * D3 + hoff;
    #pragma unroll
    for (int ks = 0; ks < 4; ++ks) qf[ks] = *(const short8*)(qrow + ks * 16 + h * 8);
  }

  f32x16 o[2];
  #pragma unroll
  for (int nt = 0; nt < 2; ++nt)
    #pragma unroll
    for (int r = 0; r < 16; ++r) o[nt][r] = 0.f;
  float l_run = 0.f;
  const f32x16 zacc = {};            // zero C for the first QK^T k-slice

  const int swzK = 8 * (q5 & 7);     // read-side XOR for both K and V tiles

  // Staging: 2 K-chunks + 2 V-chunks (16B) per thread per tile; incremental
  // pointers; source pre-XOR-permuted so linear LDS dest == swizzled layout.
  const int srow = tid >> 3, scol = (tid & 7) * 8;
  const int sswz = 8 * (srow & 7);
  const short* kptr = qkv + (size_t)(t0 * 64 + srow) * D3 + hoff + 768 + (scol ^ sswz);
  const short* vptr = vtg + ((size_t)hoff + srow) * 4096 + t0 * 64 + (scol ^ sswz);

  #define STAGE(BUF)                                                             \
    {                                                                            \
      gl_lds16(kptr,            &Ks[BUF][tid * 8]);                              \
      gl_lds16(kptr + 32 * D3,  &Ks[BUF][(tid + 256) * 8]);                      \
      gl_lds16(vptr,            &Vt[BUF][tid * 8]);                              \
      gl_lds16(vptr + 32 * 4096, &Vt[BUF][(tid + 256) * 8]);                     \
      kptr += 64 * D3;                                                           \
      vptr += 64;                                                                \
    }

  STAGE(0);
  STAGE(1);

  int cur = 0, sb = 2;               // compute buffer / stage buffer (ring of 3)
  for (int tt = t0; tt < tend; ++tt) {
    // tile tt's 4 loads done when <=4 outstanding (tile tt+1's still in flight)
    if (tt + 1 < tend) asm volatile("s_waitcnt vmcnt(4)" ::: "memory");
    else               asm volatile("s_waitcnt vmcnt(0)" ::: "memory");
    __builtin_amdgcn_s_barrier();
    if (tt + 2 < tend) STAGE(sb);

    // ---- S^T = K Q^T : C[m=j][n=q], lane holds 32 j-values for q=q5 ----
    f32x16 p[2];
    __builtin_amdgcn_s_setprio(1);
    #pragma unroll
    for (int ks = 0; ks < 4; ++ks) {
      #pragma unroll
      for (int mt = 0; mt < 2; ++mt) {
        short8 kf = *(const short8*)(&Ks[cur][(mt * 32 + q5) * 64
                                              + ((ks * 16 + h * 8) ^ swzK)]);
        p[mt] = __builtin_amdgcn_mfma_f32_32x32x16_bf16(kf, qf[ks],
                                                        ks == 0 ? zacc : p[mt], 0, 0, 0);
      }
    }
    __builtin_amdgcn_s_setprio(0);

    // ---- p = exp2(s); own-half row-sum via packed adds ----
    f32x2 s2 = {0.f, 0.f};
    #pragma unroll
    for (int mt = 0; mt < 2; ++mt)
      #pragma unroll
      for (int i = 0; i < 8; ++i) {
        float pe0 = ex2(p[mt][2 * i]);
        float pe1 = ex2(p[mt][2 * i + 1]);
        p[mt][2 * i] = pe0;
        p[mt][2 * i + 1] = pe1;
        s2 = pkadd(s2, (f32x2){pe0, pe1});
      }
    l_run += s2[0] + s2[1];

    // ---- pack P to bf16 dwords via v_cvt_pk_bf16_f32 ----
    int D[16];
    #pragma unroll
    for (int mt = 0; mt < 2; ++mt)
      #pragma unroll
      for (int c = 0; c < 4; ++c) {
        D[mt * 8 + c * 2 + 0] = cvtpk(p[mt][4 * c + 0], p[mt][4 * c + 1]);
        D[mt * 8 + c * 2 + 1] = cvtpk(p[mt][4 * c + 2], p[mt][4 * c + 3]);
      }

    // ---- O += P V : per k-step, exchange dword pairs across lane halves ----
    __builtin_amdgcn_s_setprio(1);
    #pragma unroll
    for (int ks = 0; ks < 4; ++ks) {
      union { int i[4]; short8 s; } pa;
#ifdef HAVE_PLSWAP
      v2i r02 = __builtin_amdgcn_permlane32_swap(D[4 * ks + 0], D[4 * ks + 2], false, false);
      v2i r13 = __builtin_amdgcn_permlane32_swap(D[4 * ks + 1], D[4 * ks + 3], false, false);
      pa.i[0] = r02[0];
      pa.i[1] = r13[0];
      pa.i[2] = r02[1];
      pa.i[3] = r13[1];
#else
      const bool hh = (h != 0);
      const int a0 = D[4 * ks + 0], a1 = D[4 * ks + 1];
      const int b0 = D[4 * ks + 2], b1 = D[4 * ks + 3];
      int snd0 = hh ? a0 : b0, snd1 = hh ? a1 : b1;
      int r0 = __shfl_xor(snd0, 32), r1 = __shfl_xor(snd1, 32);
      pa.i[0] = hh ? r0 : a0;
      pa.i[1] = hh ? r1 : a1;
      pa.i[2] = hh ? b0 : r0;
      pa.i[3] = hh ? b1 : r1;
#endif
      #pragma unroll
      for (int nt = 0; nt < 2; ++nt) {
        short8 vf = *(const short8*)(&Vt[cur][(nt * 32 + q5) * 64
                                              + ((ks * 16 + h * 8) ^ swzK)]);
        o[nt] = __builtin_amdgcn_mfma_f32_32x32x16_bf16(pa.s, vf, o[nt], 0, 0, 0);
      }
    }
    __builtin_amdgcn_s_setprio(0);

    cur = (cur == 2) ? 0 : cur + 1;
    sb  = (sb == 2) ? 0 : sb + 1;
  }

  // ---- epilogue: write unnormalized O (bf16) + l (f32) for this split ----
  float l_tot = l_run + __shfl_xor(l_run, 32);
  if (h == 0) Lp[(size_t)z * SEQL * NHEAD + (qbase + q5) * NHEAD + head] = l_tot;
  short* Ob = (z == 0) ? O0 : O1;
  #pragma unroll
  for (int nt = 0; nt < 2; ++nt)
    #pragma unroll
    for (int pp = 0; pp < 4; ++pp)
      #pragma unroll
      for (int r = 0; r < 4; ++r) {
        int q = qbase + r + 8 * pp + 4 * h;
        int d = hoff + nt * 32 + q5;
        Ob[(size_t)q * DIM + d] = f2bs(o[nt][4 * pp + r]);
      }
}

// ---------- combine: attb = (O0 + O1) / (l0 + l1), in place on O0 ----------
__global__ __launch_bounds__(256) void combine_kernel(short* __restrict__ O0,
                                                      const short* __restrict__ O1,
                                                      const float* __restrict__ Lp) {
  int idx = blockIdx.x * 256 + threadIdx.x;
  int e0 = idx * 8;
  if (e0 >= SEQL * DIM) return;
  int q = e0 / DIM, col = e0 % DIM, head = col >> 6;
  float lv = Lp[q * NHEAD + head] + Lp[SEQL * NHEAD + q * NHEAD + head];
  float inv = 1.0f / lv;
  short8 a = *(const short8*)(O0 + e0);
  short8 b = *(const short8*)(O1 + e0);
  short8 r;
  #pragma unroll
  for (int j = 0; j < 8; ++j) r[j] = f2bs((bf2f(a[j]) + bf2f(b[j])) * inv);
  *(short8*)(O0 + e0) = r;
}

extern "C" void kernel_launch(void* const* d_in, const int* in_sizes, int n_in,
                              void* d_out, int out_size, void* d_ws, size_t ws_size,
                              hipStream_t stream) {
  (void)in_sizes; (void)n_in; (void)out_size; (void)ws_size;
  const float* x      = (const float*)d_in[0];
  const float* w_qkv  = (const float*)d_in[1];
  const float* w_proj = (const float*)d_in[2];
  const float* b_proj = (const float*)d_in[3];
  float* out = (float*)d_out;

  short* xb   = (short*)d_ws;                    // 4096*768  (dead after QKV gemm)
  short* wqb  = xb  + (size_t)SEQL * DIM;        // 2304*768  (dead after QKV gemm)
  short* wpb  = wqb + (size_t)D3 * DIM;          // 768*768
  short* qkvb = wpb + (size_t)DIM * DIM;         // 4096*2304
  short* attb = qkvb + (size_t)SEQL * D3;        // 4096*768  (O split 0, then attended)
  // reuse dead regions during attention:
  short* Opart1 = xb;                            // 4096*768 bf16 (O split 1)
  float* Lpart  = (float*)wqb;                   // NSPLIT*4096*12 f32
  // V^T lives in d_out (12.6 MB, dead until proj GEMM): [12][64][4096] bf16
  short* vtg    = (short*)d_out;

  cvt3_kernel<<<5376, 256, 0, stream>>>(x, w_qkv, w_proj, xb, wqb, wpb);
  gemm_bt<true ><<<dim3(D3 / 128, SEQL / 128), 256, 0, stream>>>(xb, wqb, qkvb, nullptr, nullptr, SEQL, D3, DIM);
  transpose_v<<<dim3(SEQL / 64, NHEAD), 256, 0, stream>>>(qkvb, vtg);
  attn_kernel<<<dim3(32 * NHEAD * NSPLIT, 1, 1), 256, 0, stream>>>(qkvb, vtg, attb, Opart1, Lpart,
                                                                   (SEQL / 64) / NSPLIT);
  combine_kernel<<<SEQL * DIM / 8 / 256, 256, 0, stream>>>(attb, Opart1, Lpart);
  gemm_bt<false><<<dim3(DIM / 128, SEQL / 128), 256, 0, stream>>>(attb, wpb, nullptr, out, b_proj, SEQL, DIM, DIM);
}

// Round 11
// 126.456 us; speedup vs baseline: 1.2370x; 1.1683x over previous
//
#include <hip/hip_runtime.h>
#include <hip/hip_bf16.h>

using short8 = __attribute__((ext_vector_type(8))) short;
using s16x4  = __attribute__((ext_vector_type(4))) short;
using f32x2  = __attribute__((ext_vector_type(2))) float;
using f32x4  = __attribute__((ext_vector_type(4))) float;
using f32x16 = __attribute__((ext_vector_type(16))) float;
using v2i    = __attribute__((ext_vector_type(2))) int;

#define DIM   768
#define D3    2304
#define SEQL  4096
#define NHEAD 12
#define NSPLIT 2

#if defined(__has_builtin)
#  if __has_builtin(__builtin_amdgcn_permlane32_swap)
#    define HAVE_PLSWAP 1
#  endif
#endif

static __device__ __forceinline__ short f2bs(float f) {
  union { __hip_bfloat16 h; short s; } u;
  u.h = __float2bfloat16(f);
  return u.s;
}

static __device__ __forceinline__ float bf2f(short s) {
  union { unsigned u; float f; } x;
  x.u = ((unsigned)(unsigned short)s) << 16;
  return x.f;
}

static __device__ __forceinline__ int cvtpk(float lo, float hi) {
  int r;
  asm("v_cvt_pk_bf16_f32 %0, %1, %2" : "=v"(r) : "v"(lo), "v"(hi));
  return r;
}

static __device__ __forceinline__ f32x2 pkadd(f32x2 a, f32x2 b) {
  f32x2 r;
  asm("v_pk_add_f32 %0, %1, %2" : "=v"(r) : "v"(a), "v"(b));
  return r;
}

// 2^x via v_exp_f32 (glibc macro collision prevents __exp2f on this toolchain)
static __device__ __forceinline__ float ex2(float x) {
  float r;
  asm("v_exp_f32 %0, %1" : "=v"(r) : "v"(x));
  return r;
}

static __device__ __forceinline__ void gl_lds16(const void* g, void* lds) {
  __builtin_amdgcn_global_load_lds((const __attribute__((address_space(1))) void*)g,
                                   (__attribute__((address_space(3))) void*)lds, 16, 0, 0);
}

// ---------- merged fp32 -> bf16 convert for x / w_qkv / w_proj ----------
__global__ __launch_bounds__(256) void cvt3_kernel(const float* __restrict__ x,
                                                   const float* __restrict__ wq,
                                                   const float* __restrict__ wp,
                                                   short* __restrict__ xb,
                                                   short* __restrict__ wqb,
                                                   short* __restrict__ wpb) {
  int b = blockIdx.x;
  const float* src; short* dst; int base; float sc = 1.0f;
  if (b < 3072)      { src = x;  dst = xb;  base = b * 1024; }
  else if (b < 4800) { src = wq; dst = wqb; base = (b - 3072) * 1024;
                       if (base < DIM * DIM) sc = 0.125f * 1.4426950408889634f; }
  else               { src = wp; dst = wpb; base = (b - 4800) * 1024; }
  int i = base + threadIdx.x * 4;
  f32x4 v = *(const f32x4*)(src + i);
  s16x4 o;
  #pragma unroll
  for (int j = 0; j < 4; ++j) o[j] = f2bs(v[j] * sc);
  *(s16x4*)(dst + i) = o;
}

// ---------- GEMM 128x128: C[m][n] = sum_k A[m][k]*B[n][k] (bf16 in) ----------
// LDS tiles XOR-swizzled (pre-swizzled global source, swizzled reads) so the
// fragment ds_read_b128s are 2-way/bank (free) instead of 16-way.
template <bool BF16OUT>
__global__ __launch_bounds__(256) void gemm_bt(const short* __restrict__ A,
                                               const short* __restrict__ B,
                                               short* __restrict__ Cb,
                                               float* __restrict__ Cf,
                                               const float* __restrict__ bias,
                                               int M, int N, int K) {
  __shared__ short As[128 * 64];
  __shared__ short Bs[128 * 64];
  const int tid = threadIdx.x;
  const int l  = tid & 63;
  const int w  = tid >> 6;
  const int g  = l >> 4, lc = l & 15;
  const int wr = w >> 1, wc = w & 1;
  const int m0 = blockIdx.y * 128, n0 = blockIdx.x * 128;
  const int trow = tid >> 3;            // 0..31
  const int tcol = (tid & 7) * 8;
  const int sswz = 8 * (trow & 7);      // staging-source XOR (row&7 invariant under +32)
  const int rswz = 8 * (lc & 7);        // read-side XOR

  f32x4 acc[4][4];
  #pragma unroll
  for (int a = 0; a < 4; ++a)
    #pragma unroll
    for (int b = 0; b < 4; ++b) acc[a][b] = (f32x4){0.f, 0.f, 0.f, 0.f};

  for (int k0 = 0; k0 < K; k0 += 64) {
    __syncthreads();
    #pragma unroll
    for (int i = 0; i < 4; ++i) {
      int row = i * 32 + trow;
      gl_lds16(A + (size_t)(m0 + row) * K + k0 + (tcol ^ sswz), As + row * 64 + tcol);
      gl_lds16(B + (size_t)(n0 + row) * K + k0 + (tcol ^ sswz), Bs + row * 64 + tcol);
    }
    __syncthreads();
    #pragma unroll
    for (int kk = 0; kk < 2; ++kk) {
      short8 af[4], bf[4];
      #pragma unroll
      for (int mt = 0; mt < 4; ++mt)
        af[mt] = *(const short8*)(As + (wr * 64 + mt * 16 + lc) * 64 + ((kk * 32 + g * 8) ^ rswz));
      #pragma unroll
      for (int nt = 0; nt < 4; ++nt)
        bf[nt] = *(const short8*)(Bs + (wc * 64 + nt * 16 + lc) * 64 + ((kk * 32 + g * 8) ^ rswz));
      #pragma unroll
      for (int mt = 0; mt < 4; ++mt)
        #pragma unroll
        for (int nt = 0; nt < 4; ++nt)
          acc[mt][nt] = __builtin_amdgcn_mfma_f32_16x16x32_bf16(af[mt], bf[nt], acc[mt][nt], 0, 0, 0);
    }
  }

  #pragma unroll
  for (int mt = 0; mt < 4; ++mt)
    #pragma unroll
    for (int nt = 0; nt < 4; ++nt)
      #pragma unroll
      for (int r = 0; r < 4; ++r) {
        int row = m0 + wr * 64 + mt * 16 + g * 4 + r;
        int col = n0 + wc * 64 + nt * 16 + lc;
        float v = acc[mt][nt][r];
        if (BF16OUT) Cb[(size_t)row * N + col] = f2bs(v);
        else         Cf[(size_t)row * N + col] = v + bias[col];
      }
}

// ---------- GEMM 64x64 (high-occupancy variant for the small proj GEMM) ----------
// 4 waves, each computing a 32x32 quadrant (2x2 16x16 frags). Same swizzle.
template <bool BF16OUT>
__global__ __launch_bounds__(256) void gemm_bt64(const short* __restrict__ A,
                                                 const short* __restrict__ B,
                                                 short* __restrict__ Cb,
                                                 float* __restrict__ Cf,
                                                 const float* __restrict__ bias,
                                                 int M, int N, int K) {
  __shared__ short As[64 * 64];
  __shared__ short Bs[64 * 64];
  const int tid = threadIdx.x;
  const int l  = tid & 63;
  const int w  = tid >> 6;
  const int g  = l >> 4, lc = l & 15;
  const int wr = w >> 1, wc = w & 1;
  const int m0 = blockIdx.y * 64, n0 = blockIdx.x * 64;
  const int rswz = 8 * (lc & 7);

  f32x4 acc[2][2];
  #pragma unroll
  for (int a = 0; a < 2; ++a)
    #pragma unroll
    for (int b = 0; b < 2; ++b) acc[a][b] = (f32x4){0.f, 0.f, 0.f, 0.f};

  for (int k0 = 0; k0 < K; k0 += 64) {
    __syncthreads();
    #pragma unroll
    for (int i = 0; i < 2; ++i) {
      int seg = i * 256 + tid;
      int row = seg >> 3, c = (seg & 7) * 8;
      int swz = 8 * (row & 7);
      gl_lds16(A + (size_t)(m0 + row) * K + k0 + (c ^ swz), As + seg * 8);
      gl_lds16(B + (size_t)(n0 + row) * K + k0 + (c ^ swz), Bs + seg * 8);
    }
    __syncthreads();
    #pragma unroll
    for (int kk = 0; kk < 2; ++kk) {
      short8 af[2], bf[2];
      #pragma unroll
      for (int mt = 0; mt < 2; ++mt)
        af[mt] = *(const short8*)(As + (wr * 32 + mt * 16 + lc) * 64 + ((kk * 32 + g * 8) ^ rswz));
      #pragma unroll
      for (int nt = 0; nt < 2; ++nt)
        bf[nt] = *(const short8*)(Bs + (wc * 32 + nt * 16 + lc) * 64 + ((kk * 32 + g * 8) ^ rswz));
      #pragma unroll
      for (int mt = 0; mt < 2; ++mt)
        #pragma unroll
        for (int nt = 0; nt < 2; ++nt)
          acc[mt][nt] = __builtin_amdgcn_mfma_f32_16x16x32_bf16(af[mt], bf[nt], acc[mt][nt], 0, 0, 0);
    }
  }

  #pragma unroll
  for (int mt = 0; mt < 2; ++mt)
    #pragma unroll
    for (int nt = 0; nt < 2; ++nt)
      #pragma unroll
      for (int r = 0; r < 4; ++r) {
        int row = m0 + wr * 32 + mt * 16 + g * 4 + r;
        int col = n0 + wc * 32 + nt * 16 + lc;
        float v = acc[mt][nt][r];
        if (BF16OUT) Cb[(size_t)row * N + col] = f2bs(v);
        else         Cf[(size_t)row * N + col] = v + bias[col];
      }
}

// ---------- V transpose: Vtg[head][d][j] = qkv[j][1536 + head*64 + d] ----------
__global__ __launch_bounds__(256) void transpose_v(const short* __restrict__ qkv,
                                                   short* __restrict__ vtg) {
  __shared__ short T[64][72];
  const int jt = blockIdx.x, hd = blockIdx.y, tid = threadIdx.x;
  #pragma unroll
  for (int i = 0; i < 2; ++i) {
    int idx = i * 256 + tid;
    int r = idx >> 3, c = idx & 7;
    *(short8*)&T[r][8 * c] =
        *(const short8*)(qkv + (size_t)(jt * 64 + r) * D3 + 1536 + hd * 64 + 8 * c);
  }
  __syncthreads();
  #pragma unroll
  for (int i = 0; i < 2; ++i) {
    int idx = i * 256 + tid;
    int d = idx >> 3, jc = idx & 7;
    short8 v;
    #pragma unroll
    for (int e = 0; e < 8; ++e) v[e] = T[8 * jc + e][d];
    *(short8*)(vtg + ((size_t)hd * 64 + d) * 4096 + jt * 64 + 8 * jc) = v;
  }
}

// ---------- flash attention (round-8 passing version, unchanged) ----------
// grid 768 linear, XCD-chunk-swizzled -> (qtile, head, split). 256 threads
// (4 waves); wave w owns q rows qt*128 + w*32 .. +31. 3-deep LDS ring,
// ONE raw s_barrier per tile, counted vmcnt(4) (no vmcnt(0) drain in loop).
__global__ __launch_bounds__(256) void attn_kernel(const short* __restrict__ qkv,
                                                   const short* __restrict__ vtg,
                                                   short* __restrict__ O0,
                                                   short* __restrict__ O1,
                                                   float* __restrict__ Lp,
                                                   int tpb) {
  __shared__ short Ks[3][64 * 64];
  __shared__ short Vt[3][64 * 64];

  const int lin = blockIdx.x;
  const int swz = (lin & 7) * 96 + (lin >> 3);
  const int qt   = swz & 31;
  const int head = (swz >> 5) % NHEAD;
  const int z    = swz / (32 * NHEAD);

  const int tid = threadIdx.x;
  const int l = tid & 63, w = tid >> 6;
  const int h = l >> 5;
  const int q5 = l & 31;
  const int hoff = head * 64;
  const int qbase = qt * 128 + w * 32;
  const int t0 = z * tpb, tend = t0 + tpb;

  short8 qf[4];
  {
    const short* qrow = qkv + (size_t)(qbase + q5) * D3 + hoff;
    #pragma unroll
    for (int ks = 0; ks < 4; ++ks) qf[ks] = *(const short8*)(qrow + ks * 16 + h * 8);
  }

  f32x16 o[2];
  #pragma unroll
  for (int nt = 0; nt < 2; ++nt)
    #pragma unroll
    for (int r = 0; r < 16; ++r) o[nt][r] = 0.f;
  float l_run = 0.f;
  const f32x16 zacc = {};

  const int swzK = 8 * (q5 & 7);

  const int srow = tid >> 3, scol = (tid & 7) * 8;
  const int sswz = 8 * (srow & 7);
  const short* kptr = qkv + (size_t)(t0 * 64 + srow) * D3 + hoff + 768 + (scol ^ sswz);
  const short* vptr = vtg + ((size_t)hoff + srow) * 4096 + t0 * 64 + (scol ^ sswz);

  #define STAGE(BUF)                                                             \
    {                                                                            \
      gl_lds16(kptr,             &Ks[BUF][tid * 8]);                             \
      gl_lds16(kptr + 32 * D3,   &Ks[BUF][(tid + 256) * 8]);                     \
      gl_lds16(vptr,             &Vt[BUF][tid * 8]);                             \
      gl_lds16(vptr + 32 * 4096, &Vt[BUF][(tid + 256) * 8]);                     \
      kptr += 64 * D3;                                                           \
      vptr += 64;                                                                \
    }

  STAGE(0);
  STAGE(1);

  int cur = 0, sb = 2;
  for (int tt = t0; tt < tend; ++tt) {
    if (tt + 1 < tend) asm volatile("s_waitcnt vmcnt(4)" ::: "memory");
    else               asm volatile("s_waitcnt vmcnt(0)" ::: "memory");
    __builtin_amdgcn_s_barrier();
    if (tt + 2 < tend) STAGE(sb);

    f32x16 p[2];
    __builtin_amdgcn_s_setprio(1);
    #pragma unroll
    for (int ks = 0; ks < 4; ++ks) {
      #pragma unroll
      for (int mt = 0; mt < 2; ++mt) {
        short8 kf = *(const short8*)(&Ks[cur][(mt * 32 + q5) * 64
                                              + ((ks * 16 + h * 8) ^ swzK)]);
        p[mt] = __builtin_amdgcn_mfma_f32_32x32x16_bf16(kf, qf[ks],
                                                        ks == 0 ? zacc : p[mt], 0, 0, 0);
      }
    }
    __builtin_amdgcn_s_setprio(0);

    f32x2 s2 = {0.f, 0.f};
    #pragma unroll
    for (int mt = 0; mt < 2; ++mt)
      #pragma unroll
      for (int i = 0; i < 8; ++i) {
        float pe0 = ex2(p[mt][2 * i]);
        float pe1 = ex2(p[mt][2 * i + 1]);
        p[mt][2 * i] = pe0;
        p[mt][2 * i + 1] = pe1;
        s2 = pkadd(s2, (f32x2){pe0, pe1});
      }
    l_run += s2[0] + s2[1];

    int D[16];
    #pragma unroll
    for (int mt = 0; mt < 2; ++mt)
      #pragma unroll
      for (int c = 0; c < 4; ++c) {
        D[mt * 8 + c * 2 + 0] = cvtpk(p[mt][4 * c + 0], p[mt][4 * c + 1]);
        D[mt * 8 + c * 2 + 1] = cvtpk(p[mt][4 * c + 2], p[mt][4 * c + 3]);
      }

    __builtin_amdgcn_s_setprio(1);
    #pragma unroll
    for (int ks = 0; ks < 4; ++ks) {
      union { int i[4]; short8 s; } pa;
#ifdef HAVE_PLSWAP
      v2i r02 = __builtin_amdgcn_permlane32_swap(D[4 * ks + 0], D[4 * ks + 2], false, false);
      v2i r13 = __builtin_amdgcn_permlane32_swap(D[4 * ks + 1], D[4 * ks + 3], false, false);
      pa.i[0] = r02[0];
      pa.i[1] = r13[0];
      pa.i[2] = r02[1];
      pa.i[3] = r13[1];
#else
      const bool hh = (h != 0);
      const int a0 = D[4 * ks + 0], a1 = D[4 * ks + 1];
      const int b0 = D[4 * ks + 2], b1 = D[4 * ks + 3];
      int snd0 = hh ? a0 : b0, snd1 = hh ? a1 : b1;
      int r0 = __shfl_xor(snd0, 32), r1 = __shfl_xor(snd1, 32);
      pa.i[0] = hh ? r0 : a0;
      pa.i[1] = hh ? r1 : a1;
      pa.i[2] = hh ? b0 : r0;
      pa.i[3] = hh ? b1 : r1;
#endif
      #pragma unroll
      for (int nt = 0; nt < 2; ++nt) {
        short8 vf = *(const short8*)(&Vt[cur][(nt * 32 + q5) * 64
                                              + ((ks * 16 + h * 8) ^ swzK)]);
        o[nt] = __builtin_amdgcn_mfma_f32_32x32x16_bf16(pa.s, vf, o[nt], 0, 0, 0);
      }
    }
    __builtin_amdgcn_s_setprio(0);

    cur = (cur == 2) ? 0 : cur + 1;
    sb  = (sb == 2) ? 0 : sb + 1;
  }

  float l_tot = l_run + __shfl_xor(l_run, 32);
  if (h == 0) Lp[(size_t)z * SEQL * NHEAD + (qbase + q5) * NHEAD + head] = l_tot;
  short* Ob = (z == 0) ? O0 : O1;
  #pragma unroll
  for (int nt = 0; nt < 2; ++nt)
    #pragma unroll
    for (int pp = 0; pp < 4; ++pp)
      #pragma unroll
      for (int r = 0; r < 4; ++r) {
        int q = qbase + r + 8 * pp + 4 * h;
        int d = hoff + nt * 32 + q5;
        Ob[(size_t)q * DIM + d] = f2bs(o[nt][4 * pp + r]);
      }
}

// ---------- combine: attb = (O0 + O1) / (l0 + l1), in place on O0 ----------
__global__ __launch_bounds__(256) void combine_kernel(short* __restrict__ O0,
                                                      const short* __restrict__ O1,
                                                      const float* __restrict__ Lp) {
  int idx = blockIdx.x * 256 + threadIdx.x;
  int e0 = idx * 8;
  if (e0 >= SEQL * DIM) return;
  int q = e0 / DIM, col = e0 % DIM, head = col >> 6;
  float lv = Lp[q * NHEAD + head] + Lp[SEQL * NHEAD + q * NHEAD + head];
  float inv = 1.0f / lv;
  short8 a = *(const short8*)(O0 + e0);
  short8 b = *(const short8*)(O1 + e0);
  short8 r;
  #pragma unroll
  for (int j = 0; j < 8; ++j) r[j] = f2bs((bf2f(a[j]) + bf2f(b[j])) * inv);
  *(short8*)(O0 + e0) = r;
}

extern "C" void kernel_launch(void* const* d_in, const int* in_sizes, int n_in,
                              void* d_out, int out_size, void* d_ws, size_t ws_size,
                              hipStream_t stream) {
  (void)in_sizes; (void)n_in; (void)out_size; (void)ws_size;
  const float* x      = (const float*)d_in[0];
  const float* w_qkv  = (const float*)d_in[1];
  const float* w_proj = (const float*)d_in[2];
  const float* b_proj = (const float*)d_in[3];
  float* out = (float*)d_out;

  short* xb   = (short*)d_ws;                    // 4096*768  (dead after QKV gemm)
  short* wqb  = xb  + (size_t)SEQL * DIM;        // 2304*768  (dead after QKV gemm)
  short* wpb  = wqb + (size_t)D3 * DIM;          // 768*768
  short* qkvb = wpb + (size_t)DIM * DIM;         // 4096*2304
  short* attb = qkvb + (size_t)SEQL * D3;        // 4096*768  (O split 0, then attended)
  // reuse dead regions during attention:
  short* Opart1 = xb;                            // O split 1
  float* Lpart  = (float*)wqb;                   // NSPLIT*4096*12 f32
  // V^T lives in d_out (12.6 MB, dead until proj GEMM): [12][64][4096] bf16
  short* vtg    = (short*)d_out;

  cvt3_kernel<<<5376, 256, 0, stream>>>(x, w_qkv, w_proj, xb, wqb, wpb);
  gemm_bt<true ><<<dim3(D3 / 128, SEQL / 128), 256, 0, stream>>>(xb, wqb, qkvb, nullptr, nullptr, SEQL, D3, DIM);
  transpose_v<<<dim3(SEQL / 64, NHEAD), 256, 0, stream>>>(qkvb, vtg);
  attn_kernel<<<dim3(32 * NHEAD * NSPLIT, 1, 1), 256, 0, stream>>>(qkvb, vtg, attb, Opart1, Lpart,
                                                                   (SEQL / 64) / NSPLIT);
  combine_kernel<<<SEQL * DIM / 8 / 256, 256, 0, stream>>>(attb, Opart1, Lpart);
  gemm_bt64<false><<<dim3(DIM / 64, SEQL / 64), 256, 0, stream>>>(attb, wpb, nullptr, out, b_proj, SEQL, DIM, DIM);
}